// Round 1
// baseline (225.117 us; speedup 1.0000x reference)
//
#include <hip/hip_runtime.h>
#include <hip/hip_cooperative_groups.h>
#include <math.h>

namespace cg = cooperative_groups;

// out_i = clamp(out_{i-1}; a_i, a_i+1), a_i = x_i * k.  Clamp functions
// p -> min(max(p,lo),hi) compose associatively (pure min/max, exact in fp,
// no NaN inputs) -> parallel scan.
//
// R9: single cooperative-launch dispatch. The old K1 existed only to
// produce 8 KB of block aggregates but re-read all 32 MB of x to do it.
// Fused: load x once into registers, publish block aggregate (agent-scope
// atomics for cross-XCD visibility), grid.sync(), exclusive prefix over
// the aggregate array, apply, write. Traffic 96 MB -> 64 MB, 2 launches -> 1.
// Fallback to the proven 2-dispatch path if cooperative launch errors.

#define TPB 256
#define WAVES (TPB / 64)
#define SEGS 4
#define FPL 8                        // contiguous floats per lane per segment
#define SEG_ELEMS (TPB * FPL)        // 2048
#define ELEMS (SEGS * SEG_ELEMS)     // 8192 -> 1024 blocks @ T=2^23

__device__ __forceinline__ float clampf(float x, float lo, float hi) {
    return fminf(fmaxf(x, lo), hi);
}

// ---------------- fused single-dispatch cooperative kernel ----------------
__global__ __launch_bounds__(TPB, 4) void k_fused(
    const float4* __restrict__ x4,
    const float* __restrict__ kern,
    const float* __restrict__ state,
    unsigned long long* __restrict__ agg,   // float2 bit-punned, agent-scope
    float* __restrict__ out,                // T outputs + 1 new_state
    int nblocks)
{
    __shared__ float wtl[SEGS][WAVES], wth[SEGS][WAVES];
    __shared__ float rl[WAVES], rh[WAVES];
    __shared__ float s_vb;

    const int t = threadIdx.x, lane = t & 63, w = t >> 6;
    const int b = blockIdx.x;
    const float k = kern[0];
    const size_t base4 = (size_t)b * (ELEMS / 4);

    float a[SEGS][FPL];
    float eslo[SEGS], eshi[SEGS];   // compose(earlier waves, earlier lanes) per seg
    float Slo[SEGS], Shi[SEGS];     // segment totals

    // ---- (A) load once, per-segment lane pair + wave scan ----
#pragma unroll
    for (int s = 0; s < SEGS; ++s) {
        const size_t i4 = base4 + (size_t)s * (SEG_ELEMS / 4) + (size_t)t * 2;
        float4 v0 = x4[i4], v1 = x4[i4 + 1];
        a[s][0] = v0.x * k; a[s][1] = v0.y * k; a[s][2] = v0.z * k; a[s][3] = v0.w * k;
        a[s][4] = v1.x * k; a[s][5] = v1.y * k; a[s][6] = v1.z * k; a[s][7] = v1.w * k;
        float lo = a[s][0], hi = a[s][0] + 1.0f;
#pragma unroll
        for (int c = 1; c < FPL; ++c) {
            lo = clampf(lo, a[s][c], a[s][c] + 1.0f);
            hi = clampf(hi, a[s][c], a[s][c] + 1.0f);
        }
        // wave inclusive scan on lane pairs (prefix FIRST, self SECOND)
#pragma unroll
        for (int off = 1; off < 64; off <<= 1) {
            float plo = __shfl_up(lo, off);
            float phi_ = __shfl_up(hi, off);
            if (lane >= off) {
                float nlo = clampf(plo, lo, hi);
                float nhi = clampf(phi_, lo, hi);
                lo = nlo; hi = nhi;
            }
        }
        float elo = __shfl_up(lo, 1), ehi = __shfl_up(hi, 1);
        if (lane == 0) { elo = -INFINITY; ehi = INFINITY; }
        eslo[s] = elo; eshi[s] = ehi;
        if (lane == 63) { wtl[s][w] = lo; wth[s][w] = hi; }
    }
    __syncthreads();

#pragma unroll
    for (int s = 0; s < SEGS; ++s) {
        float welo = -INFINITY, wehi = INFINITY;   // earlier waves in this segment
        for (int i = 0; i < w; ++i) {
            welo = clampf(welo, wtl[s][i], wth[s][i]);
            wehi = clampf(wehi, wtl[s][i], wth[s][i]);
        }
        float llo = eslo[s], lhi = eshi[s];
        eslo[s] = clampf(welo, llo, lhi);          // compose(waves-before, lanes-before)
        eshi[s] = clampf(wehi, llo, lhi);
        float stl = -INFINITY, sth = INFINITY;     // segment total
#pragma unroll
        for (int i = 0; i < WAVES; ++i) {
            stl = clampf(stl, wtl[s][i], wth[s][i]);
            sth = clampf(sth, wtl[s][i], wth[s][i]);
        }
        Slo[s] = stl; Shi[s] = sth;
    }

    // ---- publish block aggregate (element-order compose of segment totals) ----
    if (t == 0) {
        float L = -INFINITY, H = INFINITY;
#pragma unroll
        for (int s = 0; s < SEGS; ++s) {
            L = clampf(L, Slo[s], Shi[s]);
            H = clampf(H, Slo[s], Shi[s]);
        }
        float2 p2 = make_float2(L, H);
        unsigned long long u;
        __builtin_memcpy(&u, &p2, 8);
        __hip_atomic_store(&agg[b], u, __ATOMIC_RELEASE, __HIP_MEMORY_SCOPE_AGENT);
    }

    cg::this_grid().sync();

    // ---- (B) block entry value: exclusive prefix over agg[0..b-1] ----
    {
        const int per = nblocks / TPB;   // 4 @ nblocks=1024 (contiguous chunks!)
        float lo = -INFINITY, hi = INFINITY;
#pragma unroll
        for (int c = 0; c < 4; ++c) {
            int j = t * per + c;
            if (c < per && j < b) {
                unsigned long long u =
                    __hip_atomic_load(&agg[j], __ATOMIC_RELAXED, __HIP_MEMORY_SCOPE_AGENT);
                float2 ag; __builtin_memcpy(&ag, &u, 8);
                lo = clampf(lo, ag.x, ag.y);
                hi = clampf(hi, ag.x, ag.y);
            }
        }
        // ordered wave reduce: self (earlier) FIRST, lane+off (later) SECOND
#pragma unroll
        for (int off = 1; off < 64; off <<= 1) {
            float plo = __shfl_down(lo, off);
            float phi_ = __shfl_down(hi, off);
            float nlo = clampf(lo, plo, phi_);
            float nhi = clampf(hi, plo, phi_);
            lo = nlo; hi = nhi;
        }
        if (lane == 0) { rl[w] = lo; rh[w] = hi; }
    }
    __syncthreads();
    if (t == 0) {
        float L = rl[0], H = rh[0];
#pragma unroll
        for (int i = 1; i < WAVES; ++i) {
            L = clampf(L, rl[i], rh[i]);
            H = clampf(H, rl[i], rh[i]);
        }
        s_vb = clampf(state[0], L, H);   // block entry VALUE
    }
    __syncthreads();                     // s_vb visible

    // ---- (C) thread the value, apply, write ----
    float p = s_vb;
    float wv = p;
#pragma unroll
    for (int s = 0; s < SEGS; ++s) {
        wv = clampf(p, eslo[s], eshi[s]);          // this thread's entry in segment
        float4 r0, r1;
        wv = clampf(wv, a[s][0], a[s][0] + 1.0f); r0.x = wv;
        wv = clampf(wv, a[s][1], a[s][1] + 1.0f); r0.y = wv;
        wv = clampf(wv, a[s][2], a[s][2] + 1.0f); r0.z = wv;
        wv = clampf(wv, a[s][3], a[s][3] + 1.0f); r0.w = wv;
        wv = clampf(wv, a[s][4], a[s][4] + 1.0f); r1.x = wv;
        wv = clampf(wv, a[s][5], a[s][5] + 1.0f); r1.y = wv;
        wv = clampf(wv, a[s][6], a[s][6] + 1.0f); r1.z = wv;
        wv = clampf(wv, a[s][7], a[s][7] + 1.0f); r1.w = wv;
        float4* o = (float4*)(out + (size_t)b * ELEMS + (size_t)s * SEG_ELEMS) + (size_t)t * 2;
        o[0] = r0; o[1] = r1;
        p = clampf(p, Slo[s], Shi[s]);             // advance past segment
    }

    if (b == nblocks - 1 && t == TPB - 1)
        out[(size_t)nblocks * ELEMS] = wv;         // new_state = last output
}

// ---------------- fallback: proven 2-dispatch path (R8) ----------------
__global__ __launch_bounds__(TPB) void k_agg(const float4* __restrict__ x4,
                                             const float* __restrict__ kern,
                                             float2* __restrict__ agg) {
    __shared__ float wl[SEGS][WAVES], wh[SEGS][WAVES];
    const int t = threadIdx.x, lane = t & 63, w = t >> 6;
    const int b = blockIdx.x;
    const float k = kern[0];
    const size_t base4 = (size_t)b * (ELEMS / 4);

#pragma unroll
    for (int s = 0; s < SEGS; ++s) {
        const size_t i4 = base4 + (size_t)s * (SEG_ELEMS / 4) + (size_t)t * 2;
        float4 v0 = x4[i4], v1 = x4[i4 + 1];
        float lo, hi, a;
        a = v0.x * k; lo = a; hi = a + 1.0f;
        a = v0.y * k; lo = clampf(lo, a, a + 1.0f); hi = clampf(hi, a, a + 1.0f);
        a = v0.z * k; lo = clampf(lo, a, a + 1.0f); hi = clampf(hi, a, a + 1.0f);
        a = v0.w * k; lo = clampf(lo, a, a + 1.0f); hi = clampf(hi, a, a + 1.0f);
        a = v1.x * k; lo = clampf(lo, a, a + 1.0f); hi = clampf(hi, a, a + 1.0f);
        a = v1.y * k; lo = clampf(lo, a, a + 1.0f); hi = clampf(hi, a, a + 1.0f);
        a = v1.z * k; lo = clampf(lo, a, a + 1.0f); hi = clampf(hi, a, a + 1.0f);
        a = v1.w * k; lo = clampf(lo, a, a + 1.0f); hi = clampf(hi, a, a + 1.0f);
#pragma unroll
        for (int off = 1; off < 64; off <<= 1) {
            float plo = __shfl_down(lo, off);
            float phi_ = __shfl_down(hi, off);
            float nlo = clampf(lo, plo, phi_);
            float nhi = clampf(hi, plo, phi_);
            lo = nlo; hi = nhi;
        }
        if (lane == 0) { wl[s][w] = lo; wh[s][w] = hi; }
    }
    __syncthreads();
    if (t == 0) {
        float L = -INFINITY, H = INFINITY;
#pragma unroll
        for (int s = 0; s < SEGS; ++s)
#pragma unroll
            for (int i = 0; i < WAVES; ++i) {
                L = clampf(L, wl[s][i], wh[s][i]);
                H = clampf(H, wl[s][i], wh[s][i]);
            }
        agg[b] = make_float2(L, H);
    }
}

__global__ __launch_bounds__(TPB) void k_apply(
    const float4* __restrict__ x4,
    const float* __restrict__ kern,
    const float* __restrict__ state,
    const float2* __restrict__ agg,
    float* __restrict__ out,
    int nblocks)
{
    __shared__ float rl[WAVES], rh[WAVES];
    __shared__ float wtl[SEGS][WAVES], wth[SEGS][WAVES];
    __shared__ float s_vb;

    const int t = threadIdx.x, lane = t & 63, w = t >> 6;
    const int b = blockIdx.x;
    const float k = kern[0];
    const size_t base4 = (size_t)b * (ELEMS / 4);

    {
        const int per = nblocks / TPB;
        float lo = -INFINITY, hi = INFINITY;
#pragma unroll
        for (int c = 0; c < 4; ++c) {
            int j = t * per + c;
            if (c < per && j < b) {
                float2 ag = agg[j];
                lo = clampf(lo, ag.x, ag.y);
                hi = clampf(hi, ag.x, ag.y);
            }
        }
#pragma unroll
        for (int off = 1; off < 64; off <<= 1) {
            float plo = __shfl_down(lo, off);
            float phi_ = __shfl_down(hi, off);
            float nlo = clampf(lo, plo, phi_);
            float nhi = clampf(hi, plo, phi_);
            lo = nlo; hi = nhi;
        }
        if (lane == 0) { rl[w] = lo; rh[w] = hi; }
    }
    __syncthreads();
    if (t == 0) {
        float L = rl[0], H = rh[0];
#pragma unroll
        for (int i = 1; i < WAVES; ++i) {
            L = clampf(L, rl[i], rh[i]);
            H = clampf(H, rl[i], rh[i]);
        }
        s_vb = clampf(state[0], L, H);
    }

    float a[SEGS][FPL];
    float eslo[SEGS], eshi[SEGS];
    float Slo[SEGS], Shi[SEGS];

#pragma unroll
    for (int s = 0; s < SEGS; ++s) {
        const size_t i4 = base4 + (size_t)s * (SEG_ELEMS / 4) + (size_t)t * 2;
        float4 v0 = x4[i4], v1 = x4[i4 + 1];
        a[s][0] = v0.x * k; a[s][1] = v0.y * k; a[s][2] = v0.z * k; a[s][3] = v0.w * k;
        a[s][4] = v1.x * k; a[s][5] = v1.y * k; a[s][6] = v1.z * k; a[s][7] = v1.w * k;
        float lo = a[s][0], hi = a[s][0] + 1.0f;
#pragma unroll
        for (int c = 1; c < FPL; ++c) {
            lo = clampf(lo, a[s][c], a[s][c] + 1.0f);
            hi = clampf(hi, a[s][c], a[s][c] + 1.0f);
        }
#pragma unroll
        for (int off = 1; off < 64; off <<= 1) {
            float plo = __shfl_up(lo, off);
            float phi_ = __shfl_up(hi, off);
            if (lane >= off) {
                float nlo = clampf(plo, lo, hi);
                float nhi = clampf(phi_, lo, hi);
                lo = nlo; hi = nhi;
            }
        }
        float elo = __shfl_up(lo, 1), ehi = __shfl_up(hi, 1);
        if (lane == 0) { elo = -INFINITY; ehi = INFINITY; }
        eslo[s] = elo; eshi[s] = ehi;
        if (lane == 63) { wtl[s][w] = lo; wth[s][w] = hi; }
    }
    __syncthreads();

#pragma unroll
    for (int s = 0; s < SEGS; ++s) {
        float welo = -INFINITY, wehi = INFINITY;
        for (int i = 0; i < w; ++i) {
            welo = clampf(welo, wtl[s][i], wth[s][i]);
            wehi = clampf(wehi, wtl[s][i], wth[s][i]);
        }
        float llo = eslo[s], lhi = eshi[s];
        eslo[s] = clampf(welo, llo, lhi);
        eshi[s] = clampf(wehi, llo, lhi);
        float stl = -INFINITY, sth = INFINITY;
#pragma unroll
        for (int i = 0; i < WAVES; ++i) {
            stl = clampf(stl, wtl[s][i], wth[s][i]);
            sth = clampf(sth, wtl[s][i], wth[s][i]);
        }
        Slo[s] = stl; Shi[s] = sth;
    }

    __syncthreads();
    float p = s_vb;
    float wv = p;
#pragma unroll
    for (int s = 0; s < SEGS; ++s) {
        wv = clampf(p, eslo[s], eshi[s]);
        float4 r0, r1;
        wv = clampf(wv, a[s][0], a[s][0] + 1.0f); r0.x = wv;
        wv = clampf(wv, a[s][1], a[s][1] + 1.0f); r0.y = wv;
        wv = clampf(wv, a[s][2], a[s][2] + 1.0f); r0.z = wv;
        wv = clampf(wv, a[s][3], a[s][3] + 1.0f); r0.w = wv;
        wv = clampf(wv, a[s][4], a[s][4] + 1.0f); r1.x = wv;
        wv = clampf(wv, a[s][5], a[s][5] + 1.0f); r1.y = wv;
        wv = clampf(wv, a[s][6], a[s][6] + 1.0f); r1.z = wv;
        wv = clampf(wv, a[s][7], a[s][7] + 1.0f); r1.w = wv;
        float4* o = (float4*)(out + (size_t)b * ELEMS + (size_t)s * SEG_ELEMS) + (size_t)t * 2;
        o[0] = r0; o[1] = r1;
        p = clampf(p, Slo[s], Shi[s]);
    }

    if (b == nblocks - 1 && t == TPB - 1)
        out[(size_t)nblocks * ELEMS] = wv;
}

extern "C" void kernel_launch(void* const* d_in, const int* in_sizes, int n_in,
                              void* d_out, int out_size, void* d_ws, size_t ws_size,
                              hipStream_t stream) {
    const float4* x4   = (const float4*)d_in[0];   // [1,T]
    const float* state = (const float*)d_in[1];    // [1,1]
    const float* kern  = (const float*)d_in[2];    // [1,1]
    float* out = (float*)d_out;                    // T outputs + 1 new_state

    const size_t T = (size_t)in_sizes[0];
    int nblocks = (int)(T / ELEMS);                // 1024 for T=2^23

    unsigned long long* agg_u = (unsigned long long*)d_ws;

    void* args[] = { (void*)&x4, (void*)&kern, (void*)&state,
                     (void*)&agg_u, (void*)&out, (void*)&nblocks };
    hipError_t err = hipLaunchCooperativeKernel(
        (const void*)k_fused, dim3(nblocks), dim3(TPB), args, 0, stream);

    if (err != hipSuccess) {
        // fallback: proven 2-dispatch path
        float2* agg = (float2*)d_ws;
        k_agg<<<nblocks, TPB, 0, stream>>>(x4, kern, agg);
        k_apply<<<nblocks, TPB, 0, stream>>>(x4, kern, state, agg, out, nblocks);
    }
}

// Round 2
// 112.561 us; speedup vs baseline: 2.0000x; 2.0000x over previous
//
#include <hip/hip_runtime.h>
#include <math.h>

// out_i = clamp(out_{i-1}; a_i, a_i+1), a_i = x_i * k.  Clamp functions
// p -> min(max(p,lo),hi) compose associatively (pure min/max, exact in fp,
// no NaN inputs) -> parallel scan.
//
// R10: single-pass chained scan (decoupled lookback, full-aggregate form).
//  - R9 post-mortem: cg::grid().sync() cost ~120us of stall (k_fused 135us,
//    VALUBusy 4.2%).  Traffic reduction was real (50 MB total) -> keep the
//    single-pass structure, replace the barrier with per-predecessor
//    publish/poll:
//  - block b publishes its composed clamp aggregate as ONE 64-bit
//    release-atomic; the value doubles as the ready flag (aggregates are
//    always finite floats -> all-ones sentinel is unreachable; workspace
//    slots are memset to 0xFF before launch).
//  - wave 0 of block b relaxed-polls slots j<b only (strictly-downward
//    deps).  Deadlock-free: exactly 1024 blocks at __launch_bounds__(256,4)
//    = 4 blocks/CU x 256 CU -> all co-resident.
//  - falls back to the proven R8 2-dispatch path when nblocks != 1024.

#define TPB 256
#define WAVES (TPB / 64)
#define SEGS 4
#define FPL 8                        // contiguous floats per lane per segment
#define SEG_ELEMS (TPB * FPL)        // 2048
#define ELEMS (SEGS * SEG_ELEMS)     // 8192 -> 1024 blocks @ T=2^23

#define SENT 0xFFFFFFFFFFFFFFFFull   // (-NaN,-NaN) bits: unreachable for finite aggs

__device__ __forceinline__ float clampf(float x, float lo, float hi) {
    return fminf(fmaxf(x, lo), hi);
}

// ---------------- single-pass chained-scan kernel ----------------
__global__ __launch_bounds__(TPB, 4) void k_scan1(
    const float4* __restrict__ x4,
    const float* __restrict__ kern,
    const float* __restrict__ state,
    unsigned long long* __restrict__ agg,   // float2 bit-punned; SENT = not ready
    float* __restrict__ out,                // T outputs + 1 new_state
    int nblocks)
{
    __shared__ float wtl[SEGS][WAVES], wth[SEGS][WAVES];
    __shared__ float s_vb;

    const int t = threadIdx.x, lane = t & 63, w = t >> 6;
    const int b = blockIdx.x;
    const float k = kern[0];
    const size_t base4 = (size_t)b * (ELEMS / 4);

    float a[SEGS][FPL];
    float eslo[SEGS], eshi[SEGS];   // compose(earlier waves, earlier lanes) per seg
    float Slo[SEGS], Shi[SEGS];     // segment totals

    // ---- (A) load once, per-segment lane pair + wave scan ----
#pragma unroll
    for (int s = 0; s < SEGS; ++s) {
        const size_t i4 = base4 + (size_t)s * (SEG_ELEMS / 4) + (size_t)t * 2;
        float4 v0 = x4[i4], v1 = x4[i4 + 1];
        a[s][0] = v0.x * k; a[s][1] = v0.y * k; a[s][2] = v0.z * k; a[s][3] = v0.w * k;
        a[s][4] = v1.x * k; a[s][5] = v1.y * k; a[s][6] = v1.z * k; a[s][7] = v1.w * k;
        float lo = a[s][0], hi = a[s][0] + 1.0f;
#pragma unroll
        for (int c = 1; c < FPL; ++c) {
            lo = clampf(lo, a[s][c], a[s][c] + 1.0f);
            hi = clampf(hi, a[s][c], a[s][c] + 1.0f);
        }
        // wave inclusive scan on lane pairs (prefix FIRST, self SECOND)
#pragma unroll
        for (int off = 1; off < 64; off <<= 1) {
            float plo = __shfl_up(lo, off);
            float phi_ = __shfl_up(hi, off);
            if (lane >= off) {
                float nlo = clampf(plo, lo, hi);
                float nhi = clampf(phi_, lo, hi);
                lo = nlo; hi = nhi;
            }
        }
        float elo = __shfl_up(lo, 1), ehi = __shfl_up(hi, 1);
        if (lane == 0) { elo = -INFINITY; ehi = INFINITY; }
        eslo[s] = elo; eshi[s] = ehi;
        if (lane == 63) { wtl[s][w] = lo; wth[s][w] = hi; }
    }
    __syncthreads();

#pragma unroll
    for (int s = 0; s < SEGS; ++s) {
        float welo = -INFINITY, wehi = INFINITY;   // earlier waves in this segment
        for (int i = 0; i < w; ++i) {
            welo = clampf(welo, wtl[s][i], wth[s][i]);
            wehi = clampf(wehi, wtl[s][i], wth[s][i]);
        }
        float llo = eslo[s], lhi = eshi[s];
        eslo[s] = clampf(welo, llo, lhi);          // compose(waves-before, lanes-before)
        eshi[s] = clampf(wehi, llo, lhi);
        float stl = -INFINITY, sth = INFINITY;     // segment total
#pragma unroll
        for (int i = 0; i < WAVES; ++i) {
            stl = clampf(stl, wtl[s][i], wth[s][i]);
            sth = clampf(sth, wtl[s][i], wth[s][i]);
        }
        Slo[s] = stl; Shi[s] = sth;
    }

    // ---- publish block aggregate ASAP (value doubles as ready flag) ----
    if (t == 0) {
        float L = -INFINITY, H = INFINITY;
#pragma unroll
        for (int s = 0; s < SEGS; ++s) {
            L = clampf(L, Slo[s], Shi[s]);
            H = clampf(H, Slo[s], Shi[s]);
        }
        float2 p2 = make_float2(L, H);
        unsigned long long u;
        __builtin_memcpy(&u, &p2, 8);
        __hip_atomic_store(&agg[b], u, __ATOMIC_RELEASE, __HIP_MEMORY_SCOPE_AGENT);
    }

    // ---- (B) lookback: wave 0 polls predecessors, ordered compose ----
    if (w == 0) {
        const int cpl = (nblocks + 63) >> 6;   // 16 @ nblocks=1024
        float lo = -INFINITY, hi = INFINITY;   // identity clamp
        for (int c = 0; c < cpl; ++c) {
            const int j = lane * cpl + c;      // lane owns contiguous chunk -> ordered
            if (j < b) {
                unsigned long long u;
                while ((u = __hip_atomic_load(&agg[j], __ATOMIC_RELAXED,
                                              __HIP_MEMORY_SCOPE_AGENT)) == SENT)
                    __builtin_amdgcn_s_sleep(2);
                float2 ag; __builtin_memcpy(&ag, &u, 8);
                lo = clampf(lo, ag.x, ag.y);
                hi = clampf(hi, ag.x, ag.y);
            }
        }
        // ordered wave reduce: self (earlier) FIRST, lane+off (later) SECOND.
        // OOB shfl returns self; self-compose of a clamp pair is identity.
#pragma unroll
        for (int off = 1; off < 64; off <<= 1) {
            float plo = __shfl_down(lo, off);
            float phi_ = __shfl_down(hi, off);
            float nlo = clampf(lo, plo, phi_);
            float nhi = clampf(hi, plo, phi_);
            lo = nlo; hi = nhi;
        }
        if (lane == 0) s_vb = clampf(state[0], lo, hi);   // block entry VALUE
    }
    __syncthreads();                     // s_vb visible

    // ---- (C) thread the value, apply, write ----
    float p = s_vb;
    float wv = p;
#pragma unroll
    for (int s = 0; s < SEGS; ++s) {
        wv = clampf(p, eslo[s], eshi[s]);          // this thread's entry in segment
        float4 r0, r1;
        wv = clampf(wv, a[s][0], a[s][0] + 1.0f); r0.x = wv;
        wv = clampf(wv, a[s][1], a[s][1] + 1.0f); r0.y = wv;
        wv = clampf(wv, a[s][2], a[s][2] + 1.0f); r0.z = wv;
        wv = clampf(wv, a[s][3], a[s][3] + 1.0f); r0.w = wv;
        wv = clampf(wv, a[s][4], a[s][4] + 1.0f); r1.x = wv;
        wv = clampf(wv, a[s][5], a[s][5] + 1.0f); r1.y = wv;
        wv = clampf(wv, a[s][6], a[s][6] + 1.0f); r1.z = wv;
        wv = clampf(wv, a[s][7], a[s][7] + 1.0f); r1.w = wv;
        float4* o = (float4*)(out + (size_t)b * ELEMS + (size_t)s * SEG_ELEMS) + (size_t)t * 2;
        o[0] = r0; o[1] = r1;
        p = clampf(p, Slo[s], Shi[s]);             // advance past segment
    }

    if (b == nblocks - 1 && t == TPB - 1)
        out[(size_t)nblocks * ELEMS] = wv;         // new_state = last output
}

// ---------------- fallback: proven 2-dispatch path (R8) ----------------
__global__ __launch_bounds__(TPB) void k_agg(const float4* __restrict__ x4,
                                             const float* __restrict__ kern,
                                             float2* __restrict__ agg) {
    __shared__ float wl[SEGS][WAVES], wh[SEGS][WAVES];
    const int t = threadIdx.x, lane = t & 63, w = t >> 6;
    const int b = blockIdx.x;
    const float k = kern[0];
    const size_t base4 = (size_t)b * (ELEMS / 4);

#pragma unroll
    for (int s = 0; s < SEGS; ++s) {
        const size_t i4 = base4 + (size_t)s * (SEG_ELEMS / 4) + (size_t)t * 2;
        float4 v0 = x4[i4], v1 = x4[i4 + 1];
        float lo, hi, a;
        a = v0.x * k; lo = a; hi = a + 1.0f;
        a = v0.y * k; lo = clampf(lo, a, a + 1.0f); hi = clampf(hi, a, a + 1.0f);
        a = v0.z * k; lo = clampf(lo, a, a + 1.0f); hi = clampf(hi, a, a + 1.0f);
        a = v0.w * k; lo = clampf(lo, a, a + 1.0f); hi = clampf(hi, a, a + 1.0f);
        a = v1.x * k; lo = clampf(lo, a, a + 1.0f); hi = clampf(hi, a, a + 1.0f);
        a = v1.y * k; lo = clampf(lo, a, a + 1.0f); hi = clampf(hi, a, a + 1.0f);
        a = v1.z * k; lo = clampf(lo, a, a + 1.0f); hi = clampf(hi, a, a + 1.0f);
        a = v1.w * k; lo = clampf(lo, a, a + 1.0f); hi = clampf(hi, a, a + 1.0f);
#pragma unroll
        for (int off = 1; off < 64; off <<= 1) {
            float plo = __shfl_down(lo, off);
            float phi_ = __shfl_down(hi, off);
            float nlo = clampf(lo, plo, phi_);
            float nhi = clampf(hi, plo, phi_);
            lo = nlo; hi = nhi;
        }
        if (lane == 0) { wl[s][w] = lo; wh[s][w] = hi; }
    }
    __syncthreads();
    if (t == 0) {
        float L = -INFINITY, H = INFINITY;
#pragma unroll
        for (int s = 0; s < SEGS; ++s)
#pragma unroll
            for (int i = 0; i < WAVES; ++i) {
                L = clampf(L, wl[s][i], wh[s][i]);
                H = clampf(H, wl[s][i], wh[s][i]);
            }
        agg[b] = make_float2(L, H);
    }
}

__global__ __launch_bounds__(TPB) void k_apply(
    const float4* __restrict__ x4,
    const float* __restrict__ kern,
    const float* __restrict__ state,
    const float2* __restrict__ agg,
    float* __restrict__ out,
    int nblocks)
{
    __shared__ float rl[WAVES], rh[WAVES];
    __shared__ float wtl[SEGS][WAVES], wth[SEGS][WAVES];
    __shared__ float s_vb;

    const int t = threadIdx.x, lane = t & 63, w = t >> 6;
    const int b = blockIdx.x;
    const float k = kern[0];
    const size_t base4 = (size_t)b * (ELEMS / 4);

    {
        const int per = (nblocks + TPB - 1) / TPB;
        float lo = -INFINITY, hi = INFINITY;
        for (int c = 0; c < per; ++c) {
            int j = t * per + c;
            if (j < b) {
                float2 ag = agg[j];
                lo = clampf(lo, ag.x, ag.y);
                hi = clampf(hi, ag.x, ag.y);
            }
        }
#pragma unroll
        for (int off = 1; off < 64; off <<= 1) {
            float plo = __shfl_down(lo, off);
            float phi_ = __shfl_down(hi, off);
            float nlo = clampf(lo, plo, phi_);
            float nhi = clampf(hi, plo, phi_);
            lo = nlo; hi = nhi;
        }
        if (lane == 0) { rl[w] = lo; rh[w] = hi; }
    }
    __syncthreads();
    if (t == 0) {
        float L = rl[0], H = rh[0];
#pragma unroll
        for (int i = 1; i < WAVES; ++i) {
            L = clampf(L, rl[i], rh[i]);
            H = clampf(H, rl[i], rh[i]);
        }
        s_vb = clampf(state[0], L, H);
    }

    float a[SEGS][FPL];
    float eslo[SEGS], eshi[SEGS];
    float Slo[SEGS], Shi[SEGS];

#pragma unroll
    for (int s = 0; s < SEGS; ++s) {
        const size_t i4 = base4 + (size_t)s * (SEG_ELEMS / 4) + (size_t)t * 2;
        float4 v0 = x4[i4], v1 = x4[i4 + 1];
        a[s][0] = v0.x * k; a[s][1] = v0.y * k; a[s][2] = v0.z * k; a[s][3] = v0.w * k;
        a[s][4] = v1.x * k; a[s][5] = v1.y * k; a[s][6] = v1.z * k; a[s][7] = v1.w * k;
        float lo = a[s][0], hi = a[s][0] + 1.0f;
#pragma unroll
        for (int c = 1; c < FPL; ++c) {
            lo = clampf(lo, a[s][c], a[s][c] + 1.0f);
            hi = clampf(hi, a[s][c], a[s][c] + 1.0f);
        }
#pragma unroll
        for (int off = 1; off < 64; off <<= 1) {
            float plo = __shfl_up(lo, off);
            float phi_ = __shfl_up(hi, off);
            if (lane >= off) {
                float nlo = clampf(plo, lo, hi);
                float nhi = clampf(phi_, lo, hi);
                lo = nlo; hi = nhi;
            }
        }
        float elo = __shfl_up(lo, 1), ehi = __shfl_up(hi, 1);
        if (lane == 0) { elo = -INFINITY; ehi = INFINITY; }
        eslo[s] = elo; eshi[s] = ehi;
        if (lane == 63) { wtl[s][w] = lo; wth[s][w] = hi; }
    }
    __syncthreads();

#pragma unroll
    for (int s = 0; s < SEGS; ++s) {
        float welo = -INFINITY, wehi = INFINITY;
        for (int i = 0; i < w; ++i) {
            welo = clampf(welo, wtl[s][i], wth[s][i]);
            wehi = clampf(wehi, wtl[s][i], wth[s][i]);
        }
        float llo = eslo[s], lhi = eshi[s];
        eslo[s] = clampf(welo, llo, lhi);
        eshi[s] = clampf(wehi, llo, lhi);
        float stl = -INFINITY, sth = INFINITY;
#pragma unroll
        for (int i = 0; i < WAVES; ++i) {
            stl = clampf(stl, wtl[s][i], wth[s][i]);
            sth = clampf(sth, wtl[s][i], wth[s][i]);
        }
        Slo[s] = stl; Shi[s] = sth;
    }

    __syncthreads();
    float p = s_vb;
    float wv = p;
#pragma unroll
    for (int s = 0; s < SEGS; ++s) {
        wv = clampf(p, eslo[s], eshi[s]);
        float4 r0, r1;
        wv = clampf(wv, a[s][0], a[s][0] + 1.0f); r0.x = wv;
        wv = clampf(wv, a[s][1], a[s][1] + 1.0f); r0.y = wv;
        wv = clampf(wv, a[s][2], a[s][2] + 1.0f); r0.z = wv;
        wv = clampf(wv, a[s][3], a[s][3] + 1.0f); r0.w = wv;
        wv = clampf(wv, a[s][4], a[s][4] + 1.0f); r1.x = wv;
        wv = clampf(wv, a[s][5], a[s][5] + 1.0f); r1.y = wv;
        wv = clampf(wv, a[s][6], a[s][6] + 1.0f); r1.z = wv;
        wv = clampf(wv, a[s][7], a[s][7] + 1.0f); r1.w = wv;
        float4* o = (float4*)(out + (size_t)b * ELEMS + (size_t)s * SEG_ELEMS) + (size_t)t * 2;
        o[0] = r0; o[1] = r1;
        p = clampf(p, Slo[s], Shi[s]);
    }

    if (b == nblocks - 1 && t == TPB - 1)
        out[(size_t)nblocks * ELEMS] = wv;
}

extern "C" void kernel_launch(void* const* d_in, const int* in_sizes, int n_in,
                              void* d_out, int out_size, void* d_ws, size_t ws_size,
                              hipStream_t stream) {
    const float4* x4   = (const float4*)d_in[0];   // [1,T]
    const float* state = (const float*)d_in[1];    // [1,1]
    const float* kern  = (const float*)d_in[2];    // [1,1]
    float* out = (float*)d_out;                    // T outputs + 1 new_state

    const size_t T = (size_t)in_sizes[0];
    int nblocks = (int)(T / ELEMS);                // 1024 for T=2^23

    if (nblocks == 1024 && ws_size >= (size_t)nblocks * 8) {
        // single-pass chained scan: residency guarantee holds (4 blocks/CU x 256 CU)
        unsigned long long* agg_u = (unsigned long long*)d_ws;
        hipMemsetAsync(agg_u, 0xFF, (size_t)nblocks * 8, stream);   // SENT everywhere
        k_scan1<<<nblocks, TPB, 0, stream>>>(x4, kern, state, agg_u, out, nblocks);
    } else {
        // proven 2-dispatch path
        float2* agg = (float2*)d_ws;
        k_agg<<<nblocks, TPB, 0, stream>>>(x4, kern, agg);
        k_apply<<<nblocks, TPB, 0, stream>>>(x4, kern, state, agg, out, nblocks);
    }
}

// Round 3
// 100.127 us; speedup vs baseline: 2.2483x; 1.1242x over previous
//
#include <hip/hip_runtime.h>
#include <math.h>

// out_i = clamp(out_{i-1}; a_i, a_i+1), a_i = x_i * k.  Clamp functions
// p -> min(max(p,lo),hi) compose associatively -> parallel scan.
//
// R11 = revert to proven R8 two-dispatch structure (98.4 us, absmax 0.0).
// Fusion post-mortems:
//  - R9  cooperative grid.sync: +120 us stall (k_fused 135 us, VALUBusy 4%)
//  - R10 chained publish/poll lookback: k_scan1 ~27 us vs R8's ~14.4 us
//    (serial LLC round-trips in lookback + extra memset dispatch)
// Structural analysis: timed window = ~84 us of harness 256MB poison fills
// + ~14 us controllable.  K2's re-read of x is L3-resident (32 MB << 256 MB
// LLC), so the 2-dispatch path already pays only ~64 MB of HBM traffic.
// Single-pass parity at best -> this structure is the floor.

#define TPB 256
#define WAVES (TPB / 64)
#define SEGS 4
#define FPL 8                        // contiguous floats per lane per segment
#define SEG_ELEMS (TPB * FPL)        // 2048
#define ELEMS (SEGS * SEG_ELEMS)     // 8192 -> 1024 blocks @ T=2^23

__device__ __forceinline__ float clampf(float x, float lo, float hi) {
    return fminf(fmaxf(x, lo), hi);
}

// ---------------- K1: per-block composed clamp aggregate ----------------
__global__ __launch_bounds__(TPB) void k_agg(const float4* __restrict__ x4,
                                             const float* __restrict__ kern,
                                             float2* __restrict__ agg) {
    __shared__ float wl[SEGS][WAVES], wh[SEGS][WAVES];
    const int t = threadIdx.x, lane = t & 63, w = t >> 6;
    const int b = blockIdx.x;
    const float k = kern[0];
    const size_t base4 = (size_t)b * (ELEMS / 4);

#pragma unroll
    for (int s = 0; s < SEGS; ++s) {
        const size_t i4 = base4 + (size_t)s * (SEG_ELEMS / 4) + (size_t)t * 2;
        float4 v0 = x4[i4], v1 = x4[i4 + 1];
        float lo, hi, a;
        a = v0.x * k; lo = a; hi = a + 1.0f;
        a = v0.y * k; lo = clampf(lo, a, a + 1.0f); hi = clampf(hi, a, a + 1.0f);
        a = v0.z * k; lo = clampf(lo, a, a + 1.0f); hi = clampf(hi, a, a + 1.0f);
        a = v0.w * k; lo = clampf(lo, a, a + 1.0f); hi = clampf(hi, a, a + 1.0f);
        a = v1.x * k; lo = clampf(lo, a, a + 1.0f); hi = clampf(hi, a, a + 1.0f);
        a = v1.y * k; lo = clampf(lo, a, a + 1.0f); hi = clampf(hi, a, a + 1.0f);
        a = v1.z * k; lo = clampf(lo, a, a + 1.0f); hi = clampf(hi, a, a + 1.0f);
        a = v1.w * k; lo = clampf(lo, a, a + 1.0f); hi = clampf(hi, a, a + 1.0f);
        // ordered wave reduce: self (earlier) FIRST, lane+off (later) SECOND.
        // OOB shfl returns self; self-compose of a clamp pair is identity.
#pragma unroll
        for (int off = 1; off < 64; off <<= 1) {
            float plo = __shfl_down(lo, off);
            float phi_ = __shfl_down(hi, off);
            float nlo = clampf(lo, plo, phi_);
            float nhi = clampf(hi, plo, phi_);
            lo = nlo; hi = nhi;
        }
        if (lane == 0) { wl[s][w] = lo; wh[s][w] = hi; }
    }
    __syncthreads();
    if (t == 0) {
        float L = -INFINITY, H = INFINITY;
#pragma unroll
        for (int s = 0; s < SEGS; ++s)       // (s,w) lexicographic = element order
#pragma unroll
            for (int i = 0; i < WAVES; ++i) {
                L = clampf(L, wl[s][i], wh[s][i]);
                H = clampf(H, wl[s][i], wh[s][i]);
            }
        agg[b] = make_float2(L, H);
    }
}

// ------- K2: entry from agg prefix, per-segment scan, apply + write -------
__global__ __launch_bounds__(TPB) void k_apply(
    const float4* __restrict__ x4,
    const float* __restrict__ kern,
    const float* __restrict__ state,
    const float2* __restrict__ agg,
    float* __restrict__ out,          // T outputs + 1 new_state
    int nblocks)
{
    __shared__ float rl[WAVES], rh[WAVES];
    __shared__ float wtl[SEGS][WAVES], wth[SEGS][WAVES];
    __shared__ float s_vb;

    const int t = threadIdx.x, lane = t & 63, w = t >> 6;
    const int b = blockIdx.x;
    const float k = kern[0];
    const size_t base4 = (size_t)b * (ELEMS / 4);

    // ---- (A) block entry value: exclusive prefix over agg[0..b-1] ----
    {
        const int per = nblocks / TPB;   // 4
        float lo = -INFINITY, hi = INFINITY;
#pragma unroll
        for (int c = 0; c < per; ++c) {
            int j = t * per + c;
            if (j < b) {
                float2 ag = agg[j];
                lo = clampf(lo, ag.x, ag.y);
                hi = clampf(hi, ag.x, ag.y);
            }
        }
#pragma unroll
        for (int off = 1; off < 64; off <<= 1) {
            float plo = __shfl_down(lo, off);
            float phi_ = __shfl_down(hi, off);
            float nlo = clampf(lo, plo, phi_);
            float nhi = clampf(hi, plo, phi_);
            lo = nlo; hi = nhi;
        }
        if (lane == 0) { rl[w] = lo; rh[w] = hi; }
    }
    __syncthreads();
    if (t == 0) {
        float L = rl[0], H = rh[0];
#pragma unroll
        for (int i = 1; i < WAVES; ++i) {
            L = clampf(L, rl[i], rh[i]);
            H = clampf(H, rl[i], rh[i]);
        }
        s_vb = clampf(state[0], L, H);   // block entry VALUE
    }

    // ---- (B) per-segment: load 8 contiguous floats, lane pair, wave scan ----
    float a[SEGS][FPL];
    float eslo[SEGS], eshi[SEGS];   // compose(earlier waves, earlier lanes) per seg
    float Slo[SEGS], Shi[SEGS];     // segment totals (filled after barrier)

#pragma unroll
    for (int s = 0; s < SEGS; ++s) {
        const size_t i4 = base4 + (size_t)s * (SEG_ELEMS / 4) + (size_t)t * 2;
        float4 v0 = x4[i4], v1 = x4[i4 + 1];
        a[s][0] = v0.x * k; a[s][1] = v0.y * k; a[s][2] = v0.z * k; a[s][3] = v0.w * k;
        a[s][4] = v1.x * k; a[s][5] = v1.y * k; a[s][6] = v1.z * k; a[s][7] = v1.w * k;
        float lo = a[s][0], hi = a[s][0] + 1.0f;
#pragma unroll
        for (int c = 1; c < FPL; ++c) {
            lo = clampf(lo, a[s][c], a[s][c] + 1.0f);
            hi = clampf(hi, a[s][c], a[s][c] + 1.0f);
        }
        // wave inclusive scan on lane pairs (prefix FIRST, self SECOND)
#pragma unroll
        for (int off = 1; off < 64; off <<= 1) {
            float plo = __shfl_up(lo, off);
            float phi_ = __shfl_up(hi, off);
            if (lane >= off) {
                float nlo = clampf(plo, lo, hi);
                float nhi = clampf(phi_, lo, hi);
                lo = nlo; hi = nhi;
            }
        }
        float elo = __shfl_up(lo, 1), ehi = __shfl_up(hi, 1);
        if (lane == 0) { elo = -INFINITY; ehi = INFINITY; }
        eslo[s] = elo; eshi[s] = ehi;
        if (lane == 63) { wtl[s][w] = lo; wth[s][w] = hi; }
    }
    __syncthreads();

#pragma unroll
    for (int s = 0; s < SEGS; ++s) {
        float welo = -INFINITY, wehi = INFINITY;   // earlier waves in this segment
        for (int i = 0; i < w; ++i) {
            welo = clampf(welo, wtl[s][i], wth[s][i]);
            wehi = clampf(wehi, wtl[s][i], wth[s][i]);
        }
        float llo = eslo[s], lhi = eshi[s];
        eslo[s] = clampf(welo, llo, lhi);          // compose(waves-before, lanes-before)
        eshi[s] = clampf(wehi, llo, lhi);
        float stl = -INFINITY, sth = INFINITY;     // segment total
#pragma unroll
        for (int i = 0; i < WAVES; ++i) {
            stl = clampf(stl, wtl[s][i], wth[s][i]);
            sth = clampf(sth, wtl[s][i], wth[s][i]);
        }
        Slo[s] = stl; Shi[s] = sth;
    }

    // ---- (C) thread the value, apply, coalesced-ish stores ----
    __syncthreads();                 // s_vb visible
    float p = s_vb;
    float wv = p;
#pragma unroll
    for (int s = 0; s < SEGS; ++s) {
        wv = clampf(p, eslo[s], eshi[s]);          // this thread's entry in segment
        float4 r0, r1;
        wv = clampf(wv, a[s][0], a[s][0] + 1.0f); r0.x = wv;
        wv = clampf(wv, a[s][1], a[s][1] + 1.0f); r0.y = wv;
        wv = clampf(wv, a[s][2], a[s][2] + 1.0f); r0.z = wv;
        wv = clampf(wv, a[s][3], a[s][3] + 1.0f); r0.w = wv;
        wv = clampf(wv, a[s][4], a[s][4] + 1.0f); r1.x = wv;
        wv = clampf(wv, a[s][5], a[s][5] + 1.0f); r1.y = wv;
        wv = clampf(wv, a[s][6], a[s][6] + 1.0f); r1.z = wv;
        wv = clampf(wv, a[s][7], a[s][7] + 1.0f); r1.w = wv;
        float4* o = (float4*)(out + (size_t)b * ELEMS + (size_t)s * SEG_ELEMS) + (size_t)t * 2;
        o[0] = r0; o[1] = r1;
        p = clampf(p, Slo[s], Shi[s]);             // advance past segment
    }

    if (b == nblocks - 1 && t == TPB - 1)
        out[(size_t)nblocks * ELEMS] = wv;         // new_state = last output
}

extern "C" void kernel_launch(void* const* d_in, const int* in_sizes, int n_in,
                              void* d_out, int out_size, void* d_ws, size_t ws_size,
                              hipStream_t stream) {
    const float4* x4   = (const float4*)d_in[0];   // [1,T]
    const float* state = (const float*)d_in[1];    // [1,1]
    const float* kern  = (const float*)d_in[2];    // [1,1]
    float* out = (float*)d_out;                    // T outputs + 1 new_state

    const size_t T = (size_t)in_sizes[0];
    const int nblocks = (int)(T / ELEMS);          // 1024 for T=2^23
    float2* agg = (float2*)d_ws;                   // fully written by K1 before K2 reads

    k_agg<<<nblocks, TPB, 0, stream>>>(x4, kern, agg);
    k_apply<<<nblocks, TPB, 0, stream>>>(x4, kern, state, agg, out, nblocks);
}